// Round 21
// baseline (416.061 us; speedup 1.0000x reference)
//
#include <hip/hip_runtime.h>
#include <math.h>
#include <stdint.h>

#define NPOS  32768
#define LOG2N 15
#define BATCH 8
#define TOTAL (BATCH * NPOS)          // 262144 positions
#define HE    ((size_t)16 * TOTAL)    // fp32 h buffer elements (fallback)
#define HFE   ((size_t)16 * TOTAL)    // one fp16 H buffer, elements (8 MiB)
#define WMAX  736                     // max LDS window positions (group kernel)

typedef __attribute__((ext_vector_type(8))) short    short8v;  // 8 bf16
typedef __attribute__((ext_vector_type(8))) _Float16 half8v;   // 8 fp16
typedef __attribute__((ext_vector_type(4))) _Float16 half4v;   // 4 fp16
typedef __attribute__((ext_vector_type(4))) float    f32x4;    // MFMA C/D

__device__ __forceinline__ float fast_tanh(float x) {
    float t = __expf(-2.f * x);
    return fmaf(2.f, __builtin_amdgcn_rcpf(1.f + t), -1.f);
}
__device__ __forceinline__ float fast_sigmoid(float x) {
    return __builtin_amdgcn_rcpf(1.f + __expf(-x));
}
__device__ __forceinline__ unsigned short bf16rne(float x) {
    unsigned u = __float_as_uint(x);
    u = (u + 0x7fffu + ((u >> 16) & 1u)) >> 16;
    return (unsigned short)u;
}
__device__ __forceinline__ unsigned short f16bits(float x) {
    union { _Float16 h; unsigned short u; } cv;
    cv.h = (_Float16)x;
    return cv.u;
}

// ======================================================================
// fp16-ladder defer-skip path. H_i = [pos][16] fp16, i=0..18 (152 MiB ws).
// Layers run as MFMA GROUPS (4 dispatches): first layer of group reads
// global; subsequent layers run in-LDS with right-to-left chunked in-place
// update. Snapshots H_{i+1} written for OWNED positions only.
// ======================================================================

__global__ __launch_bounds__(256) void init_f16(
    const int* __restrict__ x_int, const float* __restrict__ W0,
    const float* __restrict__ b0, _Float16* __restrict__ H0)
{
    int t0 = (blockIdx.x * 256 + threadIdx.x) * 2;
    int n0 = t0 & (NPOS - 1);
    const float sc = 1.f / 32768.f;
    float xs0  = (n0 >= 1) ? (float)x_int[t0 - 1] * sc : 0.f;
    float xs1  = (float)x_int[t0] * sc;
    float xsp0 = (n0 >= 2) ? (float)x_int[t0 - 2] * sc : 0.f;
    float xsp1 = xs0;

    half8v o[4];
#pragma unroll
    for (int c = 0; c < 16; ++c) {
        float a = xs0 + W0[c * 2 + 0] * xsp0 + W0[c * 2 + 1] * xs0 + b0[c];
        float b = xs1 + W0[c * 2 + 0] * xsp1 + W0[c * 2 + 1] * xs1 + b0[c];
        o[c >> 3][c & 7]       = (_Float16)a;
        o[2 + (c >> 3)][c & 7] = (_Float16)b;
    }
    half8v* op = (half8v*)(H0 + (size_t)t0 * 16);
    op[0] = o[0]; op[1] = o[1]; op[2] = o[2]; op[3] = o[3];
}

// ---- fused MFMA layer group -----------------------------------------------
// 1024 blocks x 256 thr (4 waves), 23 KB LDS -> 4 blocks/CU. Block owns
// [base, base+256). Phase 0 (layer iStart) reads global; phase k>=1 reads the
// in-place LDS window, right-to-left in 64-pos chunks, 1 barrier per chunk.
__global__ __launch_bounds__(256, 4) void group_mfma(
    const _Float16* __restrict__ hIn, _Float16* __restrict__ Hbase,
    const float* __restrict__ Wf, const float* __restrict__ bfv,
    const float* __restrict__ Wg, const float* __restrict__ bgv,
    int iStart, int L)
{
    __shared__ _Float16 mid[WMAX * 16];

    const int tid  = threadIdx.x;
    const int lane = tid & 63;
    const int wv   = tid >> 6;
    const int lr   = lane & 15;
    const int lg   = lane >> 4;
    const int koff = (lg & 1) * 8;
    const int sel  = lg >> 1;

    // left edges X[k] (16-aligned) and window W
    int X[5];
    X[0] = 0;
    for (int k = 1; k < L; ++k) {
        int dk = 1 << ((iStart + k + 1) % 10);
        X[k] = (X[k - 1] + dk + 15) & ~15;
    }
    const int Hlo = X[L - 1];
    const int W   = 256 + Hlo;
    const int base = blockIdx.x * 256;

#pragma unroll 1
    for (int k = 0; k < L; ++k) {
        const int i = iStart + k;
        const int d = 1 << ((i + 1) % 10);
        const float* wfL = Wf + (size_t)i * 512;
        const float* wgL = Wg + (size_t)i * 512;
        const float* bfL = bfv + i * 16;
        const float* bgL = bgv + i * 16;
        _Float16* snap = Hbase + (size_t)(i + 1) * HFE;

        // A-frags + bias for this layer
        half8v af, ag;
#pragma unroll
        for (int j = 0; j < 8; ++j) {
            af[j] = (_Float16)wfL[(lr * 16 + koff + j) * 2 + sel];
            ag[j] = (_Float16)wgL[(lr * 16 + koff + j) * 2 + sel];
        }
        f32x4 cf, cg;
#pragma unroll
        for (int r = 0; r < 4; ++r) { cf[r] = bfL[lg * 4 + r]; cg[r] = bgL[lg * 4 + r]; }

        const int xlo = X[k];
        const int nch = (W - xlo + 63) >> 6;

#pragma unroll 1
        for (int c = 0; c < nch; ++c) {
            int x0 = W - (c + 1) * 64 + wv * 16;   // this wave's tile base
            bool act = (x0 >= xlo);
            int x = x0 + lr;
            int t = base - Hlo + x;
            int n = t & (NPOS - 1);

            half4v w4;
            if (act) {
                half8v bfr;
                half4v holdv;
                if (k == 0) {
                    int tc = (t < 0) ? 0 : t;
                    if (sel == 0) {
                        bool v = (t >= 0) && (n >= d);
                        half8v xv = *(const half8v*)(hIn + (size_t)(v ? (t - d) : tc) * 16 + koff);
                        if (!v) {
#pragma unroll
                            for (int j = 0; j < 8; ++j) xv[j] = (_Float16)0.f;
                        }
                        bfr = xv;
                    } else {
                        bfr = *(const half8v*)(hIn + (size_t)tc * 16 + koff);
                    }
                    holdv = *(const half4v*)(hIn + (size_t)tc * 16 + lg * 4);
                } else {
                    if (sel == 0) {
                        bool v = (n >= d);
                        half8v xv = *(const half8v*)(&mid[(v ? (x - d) : x) * 16 + koff]);
                        if (!v) {
#pragma unroll
                            for (int j = 0; j < 8; ++j) xv[j] = (_Float16)0.f;
                        }
                        bfr = xv;
                    } else {
                        bfr = *(const half8v*)(&mid[x * 16 + koff]);
                    }
                    holdv = *(const half4v*)(&mid[x * 16 + lg * 4]);
                }

                f32x4 fAcc = __builtin_amdgcn_mfma_f32_16x16x32_f16(af, bfr, cf, 0, 0, 0);
                f32x4 gAcc = __builtin_amdgcn_mfma_f32_16x16x32_f16(ag, bfr, cg, 0, 0, 0);

                w4[0] = (_Float16)fmaf(fast_tanh(fAcc[0]), fast_sigmoid(gAcc[0]), (float)holdv[0]);
                w4[1] = (_Float16)fmaf(fast_tanh(fAcc[1]), fast_sigmoid(gAcc[1]), (float)holdv[1]);
                w4[2] = (_Float16)fmaf(fast_tanh(fAcc[2]), fast_sigmoid(gAcc[2]), (float)holdv[2]);
                w4[3] = (_Float16)fmaf(fast_tanh(fAcc[3]), fast_sigmoid(gAcc[3]), (float)holdv[3]);
            }

            __syncthreads();   // all reads of this chunk done before any write

            if (act) {
                *(half4v*)(&mid[x * 16 + lg * 4]) = w4;
                if (x0 >= Hlo)   // owned positions only -> each written once chip-wide
                    *(half4v*)(snap + (size_t)t * 16 + lg * 4) = w4;
            }
        }
        __syncthreads();   // phase boundary: writes visible before next reads
    }
}

// ---- final: f16-MFMA skip-sum + agg + f16-MFMA logits (R17 verbatim) ------
__global__ __launch_bounds__(256, 2) void final_f16(
    const _Float16* __restrict__ Hf,
    const float* __restrict__ Wsk,  const float* __restrict__ bskv,
    const float* __restrict__ Wagg, const float* __restrict__ bagg,
    const float* __restrict__ Wout, const float* __restrict__ bout,
    float* __restrict__ out)
{
    __shared__ float sv_lds[64][33];
    __shared__ unsigned short agg_bu[64 * 64];
    __shared__ float red_m[64][5];
    __shared__ float red_s[64][5];
    __shared__ float bsum[32];

    int tid  = threadIdx.x;
    int lane = tid & 63;
    int w    = tid >> 6;
    int posG = blockIdx.x * 64;
    int b    = posG >> LOG2N;
    int nb   = posG & (NPOS - 1);

    int lr = lane & 15;
    int lg = lane >> 4;

    if (tid < 32) {
        float s = 0.f;
#pragma unroll 1
        for (int i = 0; i < 19; ++i) s += bskv[i * 32 + tid];
        bsum[tid] = s;
    }

    int posGlob = posG + w * 16 + lr;

    f32x4 dsk0 = {0.f, 0.f, 0.f, 0.f};
    f32x4 dsk1 = {0.f, 0.f, 0.f, 0.f};

#pragma unroll
    for (int kt = 0; kt < 10; ++kt) {
        int i   = kt * 2 + (lg >> 1);
        int ic0 = (lg & 1) * 8;
        half8v bfr = {0, 0, 0, 0, 0, 0, 0, 0};
        half8v af0 = {0, 0, 0, 0, 0, 0, 0, 0};
        half8v af1 = {0, 0, 0, 0, 0, 0, 0, 0};
        if (i < 19) {
            bfr = *(const half8v*)(Hf + (size_t)i * HFE + (size_t)posGlob * 16 + ic0);

            const float4* wp0 = (const float4*)(Wsk + (size_t)i * 512 + (0 * 16 + lr) * 16 + ic0);
            const float4* wp1 = (const float4*)(Wsk + (size_t)i * 512 + (1 * 16 + lr) * 16 + ic0);
            float4 a0 = wp0[0], a1 = wp0[1];
            float4 c0v = wp1[0], c1v = wp1[1];
            af0[0] = (_Float16)a0.x; af0[1] = (_Float16)a0.y;
            af0[2] = (_Float16)a0.z; af0[3] = (_Float16)a0.w;
            af0[4] = (_Float16)a1.x; af0[5] = (_Float16)a1.y;
            af0[6] = (_Float16)a1.z; af0[7] = (_Float16)a1.w;
            af1[0] = (_Float16)c0v.x; af1[1] = (_Float16)c0v.y;
            af1[2] = (_Float16)c0v.z; af1[3] = (_Float16)c0v.w;
            af1[4] = (_Float16)c1v.x; af1[5] = (_Float16)c1v.y;
            af1[6] = (_Float16)c1v.z; af1[7] = (_Float16)c1v.w;
        }
        dsk0 = __builtin_amdgcn_mfma_f32_16x16x32_f16(af0, bfr, dsk0, 0, 0, 0);
        dsk1 = __builtin_amdgcn_mfma_f32_16x16x32_f16(af1, bfr, dsk1, 0, 0, 0);
    }

    __syncthreads();

    {
        int posL = w * 16 + lr;
#pragma unroll
        for (int r = 0; r < 4; ++r) {
            int sc0 = 0 * 16 + lg * 4 + r;
            int sc1 = 1 * 16 + lg * 4 + r;
            sv_lds[posL][sc0] = fmaxf(dsk0[r] + bsum[sc0], 0.f);
            sv_lds[posL][sc1] = fmaxf(dsk1[r] + bsum[sc1], 0.f);
        }
    }
    __syncthreads();

    {
        float sv[32];
#pragma unroll
        for (int sch = 0; sch < 32; ++sch) sv[sch] = sv_lds[lane][sch];

        float r16[16];
#pragma unroll
        for (int a = 0; a < 16; ++a) {
            int ac = w * 16 + a;
            float acc = bagg[ac];
#pragma unroll
            for (int sch = 0; sch < 32; ++sch)
                acc = fmaf(Wagg[ac * 32 + sch], sv[sch], acc);
            r16[a] = fmaxf(acc, 0.f);
        }
#pragma unroll
        for (int q = 0; q < 8; ++q) {
            unsigned pk = (unsigned)f16bits(r16[2 * q]) |
                          ((unsigned)f16bits(r16[2 * q + 1]) << 16);
            int icbyte = (w * 16 + 2 * q) * 2;
            int addr   = lane * 128 + (icbyte ^ ((lane & 7) << 4));
            *(unsigned*)(&agg_bu[addr >> 1]) = pk;
        }
    }
    __syncthreads();

    int c0 = w * 64;
    half8v afr[4][2];
#pragma unroll
    for (int ct = 0; ct < 4; ++ct) {
#pragma unroll
        for (int kf = 0; kf < 2; ++kf) {
            int cls = c0 + ct * 16 + lr;
            int k0  = kf * 32 + lg * 8;
            const float4* wp = (const float4*)(Wout + (size_t)cls * 64 + k0);
            float4 w0 = wp[0], w1 = wp[1];
            half8v af;
            af[0] = (_Float16)w0.x; af[1] = (_Float16)w0.y;
            af[2] = (_Float16)w0.z; af[3] = (_Float16)w0.w;
            af[4] = (_Float16)w1.x; af[5] = (_Float16)w1.y;
            af[6] = (_Float16)w1.z; af[7] = (_Float16)w1.w;
            afr[ct][kf] = af;
        }
    }

    f32x4 acc[4][4];
#pragma unroll
    for (int pt = 0; pt < 4; ++pt) {
        int pos = pt * 16 + lr;
        int sw  = (pos & 7) << 4;
        const half8v* bp0 = (const half8v*)(&agg_bu[(pos * 128 + ((0 * 64 + lg * 16) ^ sw)) >> 1]);
        const half8v* bp1 = (const half8v*)(&agg_bu[(pos * 128 + ((1 * 64 + lg * 16) ^ sw)) >> 1]);
        half8v bf0 = *bp0;
        half8v bf1 = *bp1;
#pragma unroll
        for (int ct = 0; ct < 4; ++ct) {
            f32x4 c;
#pragma unroll
            for (int r = 0; r < 4; ++r) c[r] = bout[c0 + ct * 16 + lg * 4 + r];
            c = __builtin_amdgcn_mfma_f32_16x16x32_f16(afr[ct][0], bf0, c, 0, 0, 0);
            c = __builtin_amdgcn_mfma_f32_16x16x32_f16(afr[ct][1], bf1, c, 0, 0, 0);
            acc[pt][ct] = c;
        }
    }

#pragma unroll
    for (int pt = 0; pt < 4; ++pt) {
        float m = -1e30f;
#pragma unroll
        for (int ct = 0; ct < 4; ++ct)
#pragma unroll
            for (int r = 0; r < 4; ++r) m = fmaxf(m, acc[pt][ct][r]);
        m = fmaxf(m, __shfl_xor(m, 16));
        m = fmaxf(m, __shfl_xor(m, 32));
        float s = 0.f;
#pragma unroll
        for (int ct = 0; ct < 4; ++ct)
#pragma unroll
            for (int r = 0; r < 4; ++r) s += __expf(acc[pt][ct][r] - m);
        s += __shfl_xor(s, 16);
        s += __shfl_xor(s, 32);
        int pos = pt * 16 + lr;
        red_m[pos][w] = m;
        red_s[pos][w] = s;
    }
    __syncthreads();

#pragma unroll
    for (int pt = 0; pt < 4; ++pt) {
        int pos = pt * 16 + lr;
        float M = fmaxf(fmaxf(red_m[pos][0], red_m[pos][1]),
                        fmaxf(red_m[pos][2], red_m[pos][3]));
        float S = 0.f;
#pragma unroll
        for (int k = 0; k < 4; ++k) S += red_s[pos][k] * __expf(red_m[pos][k] - M);
        float logZ = M + __logf(S);

        int n = nb + pos;
#pragma unroll
        for (int ct = 0; ct < 4; ++ct) {
#pragma unroll
            for (int r = 0; r < 4; ++r) {
                int cls = c0 + ct * 16 + lg * 4 + r;
                out[((size_t)(b * 256 + cls)) * NPOS + n] = acc[pt][ct][r] - logZ;
            }
        }
    }
}

// ======================================================================
// R8 fallback path (ch-major, skip-RMW, bf16 final) — safety net only
// ======================================================================
__global__ __launch_bounds__(256) void init_kernel2(
    const int* __restrict__ x_int, const float* __restrict__ W0,
    const float* __restrict__ b0, float* __restrict__ h)
{
    int t0 = (blockIdx.x * 256 + threadIdx.x) * 2;
    int n0 = t0 & (NPOS - 1);
    const float sc = 1.f / 32768.f;
    float xs0  = (n0 >= 1) ? (float)x_int[t0 - 1] * sc : 0.f;
    float xs1  = (float)x_int[t0] * sc;
    float xsp0 = (n0 >= 2) ? (float)x_int[t0 - 2] * sc : 0.f;
    float xsp1 = xs0;
#pragma unroll
    for (int c = 0; c < 16; ++c) {
        float2 o;
        o.x = xs0 + W0[c * 2 + 0] * xsp0 + W0[c * 2 + 1] * xs0 + b0[c];
        o.y = xs1 + W0[c * 2 + 0] * xsp1 + W0[c * 2 + 1] * xs1 + b0[c];
        *(float2*)(h + (size_t)c * TOTAL + t0) = o;
    }
}

__global__ __launch_bounds__(256, 2) void layer_kernel2(
    const float* __restrict__ hIn, float* __restrict__ hOut,
    float* __restrict__ skip,
    const float* __restrict__ wf, const float* __restrict__ bfv,
    const float* __restrict__ wg, const float* __restrict__ bgv,
    const float* __restrict__ wsk, const float* __restrict__ bskv,
    int d, int firstLayer)
{
    int t0 = (blockIdx.x * 256 + threadIdx.x) * 2;
    int n0 = t0 & (NPOS - 1);

    float2 hc[16], hp[16];
#pragma unroll
    for (int ic = 0; ic < 16; ++ic)
        hc[ic] = *(const float2*)(hIn + (size_t)ic * TOTAL + t0);

    if (d == 1) {
        bool v = (n0 >= 1);
        int tm = v ? (t0 - 1) : t0;
#pragma unroll
        for (int ic = 0; ic < 16; ++ic) {
            float x = hIn[(size_t)ic * TOTAL + tm];
            hp[ic].x = v ? x : 0.f;
            hp[ic].y = hc[ic].x;
        }
    } else {
        bool v = (n0 >= d);
        int tm = v ? (t0 - d) : t0;
#pragma unroll
        for (int ic = 0; ic < 16; ++ic) {
            float2 x = *(const float2*)(hIn + (size_t)ic * TOTAL + tm);
            hp[ic].x = v ? x.x : 0.f;
            hp[ic].y = v ? x.y : 0.f;
        }
    }

    float2 fa[16], ga[16];
#pragma unroll
    for (int c = 0; c < 16; ++c) {
        fa[c].x = fa[c].y = bfv[c];
        ga[c].x = ga[c].y = bgv[c];
    }
#pragma unroll
    for (int c = 0; c < 16; ++c) {
#pragma unroll
        for (int ic = 0; ic < 16; ++ic) {
            float wf0 = wf[(c * 16 + ic) * 2 + 0];
            float wf1 = wf[(c * 16 + ic) * 2 + 1];
            float wg0 = wg[(c * 16 + ic) * 2 + 0];
            float wg1 = wg[(c * 16 + ic) * 2 + 1];
            fa[c].x = fmaf(wf0, hp[ic].x, fa[c].x);
            fa[c].x = fmaf(wf1, hc[ic].x, fa[c].x);
            fa[c].y = fmaf(wf0, hp[ic].y, fa[c].y);
            fa[c].y = fmaf(wf1, hc[ic].y, fa[c].y);
            ga[c].x = fmaf(wg0, hp[ic].x, ga[c].x);
            ga[c].x = fmaf(wg1, hc[ic].x, ga[c].x);
            ga[c].y = fmaf(wg0, hp[ic].y, ga[c].y);
            ga[c].y = fmaf(wg1, hc[ic].y, ga[c].y);
        }
    }

#pragma unroll
    for (int c = 0; c < 16; ++c) {
        float2 o;
        o.x = fmaf(fast_tanh(fa[c].x), fast_sigmoid(ga[c].x), hc[c].x);
        o.y = fmaf(fast_tanh(fa[c].y), fast_sigmoid(ga[c].y), hc[c].y);
        *(float2*)(hOut + (size_t)c * TOTAL + t0) = o;
    }

#pragma unroll
    for (int sch = 0; sch < 32; ++sch) {
        float2 acc;
        acc.x = acc.y = bskv[sch];
#pragma unroll
        for (int ic = 0; ic < 16; ++ic) {
            float wv = wsk[sch * 16 + ic];
            acc.x = fmaf(wv, hc[ic].x, acc.x);
            acc.y = fmaf(wv, hc[ic].y, acc.y);
        }
        float* sp = skip + (size_t)sch * TOTAL + t0;
        if (firstLayer) {
            *(float2*)sp = acc;
        } else {
            float2 old = *(const float2*)sp;
            acc.x += old.x; acc.y += old.y;
            *(float2*)sp = acc;
        }
    }
}

__global__ __launch_bounds__(256, 2) void final_kernel(
    const float* __restrict__ skip,
    const float* __restrict__ Wagg, const float* __restrict__ bagg,
    const float* __restrict__ Wout, const float* __restrict__ bout,
    float* __restrict__ out)
{
    __shared__ unsigned short agg_bu[64 * 64];
    __shared__ float red_m[64][5];
    __shared__ float red_s[64][5];

    int tid  = threadIdx.x;
    int lane = tid & 63;
    int w    = tid >> 6;
    int posG = blockIdx.x * 64;
    int b    = posG >> LOG2N;
    int nb   = posG & (NPOS - 1);

    {
        int pos = posG + lane;
        float sv[32];
#pragma unroll
        for (int sch = 0; sch < 32; ++sch)
            sv[sch] = fmaxf(skip[(size_t)sch * TOTAL + pos], 0.f);

        float r16[16];
#pragma unroll
        for (int a = 0; a < 16; ++a) {
            int ac = w * 16 + a;
            float acc = bagg[ac];
#pragma unroll
            for (int sch = 0; sch < 32; ++sch)
                acc = fmaf(Wagg[ac * 32 + sch], sv[sch], acc);
            r16[a] = fmaxf(acc, 0.f);
        }
#pragma unroll
        for (int q = 0; q < 8; ++q) {
            unsigned pk = (unsigned)bf16rne(r16[2 * q]) |
                          ((unsigned)bf16rne(r16[2 * q + 1]) << 16);
            int icbyte = (w * 16 + 2 * q) * 2;
            int addr   = lane * 128 + (icbyte ^ ((lane & 7) << 4));
            *(unsigned*)(&agg_bu[addr >> 1]) = pk;
        }
    }
    __syncthreads();

    int lr = lane & 15;
    int lg = lane >> 4;
    int c0 = w * 64;
    short8v afr[4][2];
#pragma unroll
    for (int ct = 0; ct < 4; ++ct) {
#pragma unroll
        for (int kf = 0; kf < 2; ++kf) {
            int cls = c0 + ct * 16 + lr;
            int k0  = kf * 32 + lg * 8;
            const float4* wp = (const float4*)(Wout + (size_t)cls * 64 + k0);
            float4 w0 = wp[0], w1 = wp[1];
            short8v af;
            af[0] = (short)bf16rne(w0.x); af[1] = (short)bf16rne(w0.y);
            af[2] = (short)bf16rne(w0.z); af[3] = (short)bf16rne(w0.w);
            af[4] = (short)bf16rne(w1.x); af[5] = (short)bf16rne(w1.y);
            af[6] = (short)bf16rne(w1.z); af[7] = (short)bf16rne(w1.w);
            afr[ct][kf] = af;
        }
    }

    f32x4 acc[4][4];
#pragma unroll
    for (int pt = 0; pt < 4; ++pt) {
        int pos = pt * 16 + lr;
        int sw  = (pos & 7) << 4;
        const short8v* bp0 = (const short8v*)(&agg_bu[(pos * 128 + ((0 * 64 + lg * 16) ^ sw)) >> 1]);
        const short8v* bp1 = (const short8v*)(&agg_bu[(pos * 128 + ((1 * 64 + lg * 16) ^ sw)) >> 1]);
        short8v bf0 = *bp0;
        short8v bf1 = *bp1;
#pragma unroll
        for (int ct = 0; ct < 4; ++ct) {
            f32x4 c;
#pragma unroll
            for (int r = 0; r < 4; ++r) c[r] = bout[c0 + ct * 16 + lg * 4 + r];
            c = __builtin_amdgcn_mfma_f32_16x16x32_bf16(afr[ct][0], bf0, c, 0, 0, 0);
            c = __builtin_amdgcn_mfma_f32_16x16x32_bf16(afr[ct][1], bf1, c, 0, 0, 0);
            acc[pt][ct] = c;
        }
    }

#pragma unroll
    for (int pt = 0; pt < 4; ++pt) {
        float m = -1e30f;
#pragma unroll
        for (int ct = 0; ct < 4; ++ct)
#pragma unroll
            for (int r = 0; r < 4; ++r) m = fmaxf(m, acc[pt][ct][r]);
        m = fmaxf(m, __shfl_xor(m, 16));
        m = fmaxf(m, __shfl_xor(m, 32));
        float s = 0.f;
#pragma unroll
        for (int ct = 0; ct < 4; ++ct)
#pragma unroll
            for (int r = 0; r < 4; ++r) s += __expf(acc[pt][ct][r] - m);
        s += __shfl_xor(s, 16);
        s += __shfl_xor(s, 32);
        int pos = pt * 16 + lr;
        red_m[pos][w] = m;
        red_s[pos][w] = s;
    }
    __syncthreads();

#pragma unroll
    for (int pt = 0; pt < 4; ++pt) {
        int pos = pt * 16 + lr;
        float M = fmaxf(fmaxf(red_m[pos][0], red_m[pos][1]),
                        fmaxf(red_m[pos][2], red_m[pos][3]));
        float S = 0.f;
#pragma unroll
        for (int k = 0; k < 4; ++k) S += red_s[pos][k] * __expf(red_m[pos][k] - M);
        float logZ = M + __logf(S);

        int n = nb + pos;
#pragma unroll
        for (int ct = 0; ct < 4; ++ct) {
#pragma unroll
            for (int r = 0; r < 4; ++r) {
                int cls = c0 + ct * 16 + lg * 4 + r;
                out[((size_t)(b * 256 + cls)) * NPOS + n] = acc[pt][ct][r] - logZ;
            }
        }
    }
}

extern "C" void kernel_launch(void* const* d_in, const int* in_sizes, int n_in,
                              void* d_out, int out_size, void* d_ws, size_t ws_size,
                              hipStream_t stream)
{
    const int*   x_int = (const int*)  d_in[0];
    const float* W0    = (const float*)d_in[1];
    const float* b0    = (const float*)d_in[2];
    const float* Wf    = (const float*)d_in[3];
    const float* bfv   = (const float*)d_in[4];
    const float* Wg    = (const float*)d_in[5];
    const float* bgv   = (const float*)d_in[6];
    const float* Wsk   = (const float*)d_in[7];
    const float* bskv  = (const float*)d_in[8];
    const float* Wagg  = (const float*)d_in[9];
    const float* bagg  = (const float*)d_in[10];
    const float* Wout  = (const float*)d_in[11];
    const float* bout  = (const float*)d_in[12];
    float* out = (float*)d_out;

    const size_t needF16 = 19 * HFE * sizeof(_Float16);   // 152 MiB
    const int grid2 = TOTAL / (256 * 2);                  // 512 blocks

    if (ws_size >= needF16) {
        // ---------- fp16-ladder with fused MFMA layer groups ----------
        _Float16* Hf = (_Float16*)d_ws;    // H_i at Hf + i*HFE

        init_f16<<<grid2, 256, 0, stream>>>(x_int, W0, b0, Hf);

        // groups: big-dilation layer first (reads global, no halo cost)
        const int gs[4] = {0, 5, 8, 13};
        const int gl[4] = {5, 3, 5, 5};
        for (int g = 0; g < 4; ++g) {
            group_mfma<<<TOTAL / 256, 256, 0, stream>>>(
                Hf + (size_t)gs[g] * HFE, Hf,
                Wf, bfv, Wg, bgv, gs[g], gl[g]);
        }
        final_f16<<<TOTAL / 64, 256, 0, stream>>>(
            Hf, Wsk, bskv, Wagg, bagg, Wout, bout, out);
    } else {
        // ---------- R8 fallback (ch-major, skip-RMW) ----------
        const size_t skE = (size_t)32 * TOTAL;
        float* skipb = (float*)d_ws;
        float *hA, *hB;
        if (ws_size >= (skE + 2 * HE) * sizeof(float)) {
            hA = skipb + skE;
            hB = hA + HE;
        } else {
            hA = out + ((size_t)out_size - 2 * HE);
            hB = hA + HE;
        }

        init_kernel2<<<grid2, 256, 0, stream>>>(x_int, W0, b0, hA);
        float* hin = hA;
        float* hout = hB;
        for (int i = 0; i < 19; ++i) {
            int d = 1 << ((i + 1) % 10);
            layer_kernel2<<<grid2, 256, 0, stream>>>(
                hin, hout, skipb,
                Wf + (size_t)i * 512, bfv + (size_t)i * 16,
                Wg + (size_t)i * 512, bgv + (size_t)i * 16,
                Wsk + (size_t)i * 512, bskv + (size_t)i * 32,
                d, (i == 0) ? 1 : 0);
            float* tmp = hin; hin = hout; hout = tmp;
        }
        final_kernel<<<TOTAL / 64, 256, 0, stream>>>(
            skipb, Wagg, bagg, Wout, bout, out);
    }
}

// Round 22
// 398.349 us; speedup vs baseline: 1.0445x; 1.0445x over previous
//
#include <hip/hip_runtime.h>
#include <math.h>
#include <stdint.h>

#define NPOS  32768
#define LOG2N 15
#define BATCH 8
#define TOTAL (BATCH * NPOS)          // 262144 positions
#define HE    ((size_t)16 * TOTAL)    // fp32 h buffer elements (fallback)
#define HFE   ((size_t)16 * TOTAL)    // one fp16 H buffer, elements (8 MiB)

typedef __attribute__((ext_vector_type(8))) short    short8v;  // 8 bf16
typedef __attribute__((ext_vector_type(8))) _Float16 half8v;   // 8 fp16
typedef __attribute__((ext_vector_type(4))) _Float16 half4v;   // 4 fp16
typedef __attribute__((ext_vector_type(4))) float    f32x4;    // MFMA C/D

__device__ __forceinline__ float fast_tanh(float x) {
    float t = __expf(-2.f * x);
    return fmaf(2.f, __builtin_amdgcn_rcpf(1.f + t), -1.f);
}
__device__ __forceinline__ float fast_sigmoid(float x) {
    return __builtin_amdgcn_rcpf(1.f + __expf(-x));
}
__device__ __forceinline__ unsigned short bf16rne(float x) {
    unsigned u = __float_as_uint(x);
    u = (u + 0x7fffu + ((u >> 16) & 1u)) >> 16;
    return (unsigned short)u;
}
__device__ __forceinline__ unsigned short f16bits(float x) {
    union { _Float16 h; unsigned short u; } cv;
    cv.h = (_Float16)x;
    return cv.u;
}

// ======================================================================
// fp16-ladder defer-skip path. H_i = [pos][16] fp16, i=0..18 (152 MiB ws).
// Layers run as MFMA PAIRS (9 dispatches, R20-validated). Final has a
// LDS-transposed epilogue for 256B-coalesced out writes.
// ======================================================================

__global__ __launch_bounds__(256) void init_f16(
    const int* __restrict__ x_int, const float* __restrict__ W0,
    const float* __restrict__ b0, _Float16* __restrict__ H0)
{
    int t0 = (blockIdx.x * 256 + threadIdx.x) * 2;
    int n0 = t0 & (NPOS - 1);
    const float sc = 1.f / 32768.f;
    float xs0  = (n0 >= 1) ? (float)x_int[t0 - 1] * sc : 0.f;
    float xs1  = (float)x_int[t0] * sc;
    float xsp0 = (n0 >= 2) ? (float)x_int[t0 - 2] * sc : 0.f;
    float xsp1 = xs0;

    half8v o[4];
#pragma unroll
    for (int c = 0; c < 16; ++c) {
        float a = xs0 + W0[c * 2 + 0] * xsp0 + W0[c * 2 + 1] * xs0 + b0[c];
        float b = xs1 + W0[c * 2 + 0] * xsp1 + W0[c * 2 + 1] * xs1 + b0[c];
        o[c >> 3][c & 7]       = (_Float16)a;
        o[2 + (c >> 3)][c & 7] = (_Float16)b;
    }
    half8v* op = (half8v*)(H0 + (size_t)t0 * 16);
    op[0] = o[0]; op[1] = o[1]; op[2] = o[2]; op[3] = o[3];
}

// ---- fused MFMA layer pair (R20 verbatim) ---------------------------------
__global__ __launch_bounds__(256, 4) void pair_mfma(
    const _Float16* __restrict__ hIn,
    _Float16* __restrict__ hAout, _Float16* __restrict__ hBout,
    const float* __restrict__ wfA, const float* __restrict__ bfA,
    const float* __restrict__ wgA, const float* __restrict__ bgA,
    const float* __restrict__ wfB, const float* __restrict__ bfB,
    const float* __restrict__ wgB, const float* __restrict__ bgB,
    int dA, int dB, int haloR)
{
    __shared__ _Float16 mid[512][16];     // [loc][ch], 32B rows

    const int tid  = threadIdx.x;
    const int lane = tid & 63;
    const int wv   = tid >> 6;
    const int lr   = lane & 15;
    const int lg   = lane >> 4;
    const int koff = (lg & 1) * 8;
    const int sel  = lg >> 1;

    const int base  = blockIdx.x * 256;
    const int tiles = (256 + haloR) >> 4;

    half8v afA, agA;
#pragma unroll
    for (int j = 0; j < 8; ++j) {
        afA[j] = (_Float16)wfA[(lr * 16 + koff + j) * 2 + sel];
        agA[j] = (_Float16)wgA[(lr * 16 + koff + j) * 2 + sel];
    }
    f32x4 cfA, cgA;
#pragma unroll
    for (int r = 0; r < 4; ++r) { cfA[r] = bfA[lg * 4 + r]; cgA[r] = bgA[lg * 4 + r]; }

    // ---- phase A: layer iA over [base-haloR, base+256)
#pragma unroll 1
    for (int tt = wv; tt < tiles; tt += 4) {
        int loc0 = tt * 16;
        int t  = base - haloR + loc0 + lr;
        int tc = (t < 0) ? 0 : t;
        int n  = t & (NPOS - 1);

        half8v bfr;
        if (sel == 0) {
            bool v = (t >= 0) && (n >= dA);
            half8v x = *(const half8v*)(hIn + (size_t)(v ? (t - dA) : tc) * 16 + koff);
            if (!v) {
#pragma unroll
                for (int j = 0; j < 8; ++j) x[j] = (_Float16)0.f;
            }
            bfr = x;
        } else {
            bfr = *(const half8v*)(hIn + (size_t)tc * 16 + koff);
        }

        f32x4 fAcc = __builtin_amdgcn_mfma_f32_16x16x32_f16(afA, bfr, cfA, 0, 0, 0);
        f32x4 gAcc = __builtin_amdgcn_mfma_f32_16x16x32_f16(agA, bfr, cgA, 0, 0, 0);

        const _Float16* hold = hIn + (size_t)tc * 16 + lg * 4;
        half4v w4;
        {
            w4[0] = (_Float16)fmaf(fast_tanh(fAcc[0]), fast_sigmoid(gAcc[0]), (float)hold[0]);
            w4[1] = (_Float16)fmaf(fast_tanh(fAcc[1]), fast_sigmoid(gAcc[1]), (float)hold[1]);
            w4[2] = (_Float16)fmaf(fast_tanh(fAcc[2]), fast_sigmoid(gAcc[2]), (float)hold[2]);
            w4[3] = (_Float16)fmaf(fast_tanh(fAcc[3]), fast_sigmoid(gAcc[3]), (float)hold[3]);
        }
        *(half4v*)(&mid[loc0 + lr][lg * 4]) = w4;
        if (t >= 0)
            *(half4v*)(hAout + (size_t)t * 16 + lg * 4) = w4;
    }
    __syncthreads();

    half8v afB, agB;
#pragma unroll
    for (int j = 0; j < 8; ++j) {
        afB[j] = (_Float16)wfB[(lr * 16 + koff + j) * 2 + sel];
        agB[j] = (_Float16)wgB[(lr * 16 + koff + j) * 2 + sel];
    }
    f32x4 cfB, cgB;
#pragma unroll
    for (int r = 0; r < 4; ++r) { cfB[r] = bfB[lg * 4 + r]; cgB[r] = bgB[lg * 4 + r]; }

    // ---- phase B: layer iB over [base, base+256) from LDS
#pragma unroll
    for (int nt = 0; nt < 4; ++nt) {
        int local0 = wv * 64 + nt * 16;
        int t   = base + local0 + lr;
        int n   = t & (NPOS - 1);
        int loc = haloR + local0 + lr;

        half8v bfr;
        if (sel == 0) {
            bool v = (n >= dB);
            half8v x = *(const half8v*)(&mid[v ? (loc - dB) : loc][koff]);
            if (!v) {
#pragma unroll
                for (int j = 0; j < 8; ++j) x[j] = (_Float16)0.f;
            }
            bfr = x;
        } else {
            bfr = *(const half8v*)(&mid[loc][koff]);
        }

        f32x4 fAcc = __builtin_amdgcn_mfma_f32_16x16x32_f16(afB, bfr, cfB, 0, 0, 0);
        f32x4 gAcc = __builtin_amdgcn_mfma_f32_16x16x32_f16(agB, bfr, cgB, 0, 0, 0);

        const _Float16* hold = &mid[loc][lg * 4];
        half4v w4;
        {
            w4[0] = (_Float16)fmaf(fast_tanh(fAcc[0]), fast_sigmoid(gAcc[0]), (float)hold[0]);
            w4[1] = (_Float16)fmaf(fast_tanh(fAcc[1]), fast_sigmoid(gAcc[1]), (float)hold[1]);
            w4[2] = (_Float16)fmaf(fast_tanh(fAcc[2]), fast_sigmoid(gAcc[2]), (float)hold[2]);
            w4[3] = (_Float16)fmaf(fast_tanh(fAcc[3]), fast_sigmoid(gAcc[3]), (float)hold[3]);
        }
        *(half4v*)(hBout + (size_t)t * 16 + lg * 4) = w4;
    }
}

// ---- final: f16-MFMA skip-sum + agg + f16-MFMA logits + coalesced write ---
__global__ __launch_bounds__(256, 2) void final_f16(
    const _Float16* __restrict__ Hf,
    const float* __restrict__ Wsk,  const float* __restrict__ bskv,
    const float* __restrict__ Wagg, const float* __restrict__ bagg,
    const float* __restrict__ Wout, const float* __restrict__ bout,
    float* __restrict__ out)
{
    __shared__ float sv_lds[64][33];
    __shared__ unsigned short agg_bu[64 * 64];
    __shared__ float red_m[64][5];
    __shared__ float red_s[64][5];
    __shared__ float bsum[32];
    __shared__ float tr_lds[4][16][66];   // per-wave transpose buffer

    int tid  = threadIdx.x;
    int lane = tid & 63;
    int w    = tid >> 6;
    int posG = blockIdx.x * 64;
    int b    = posG >> LOG2N;
    int nb   = posG & (NPOS - 1);

    int lr = lane & 15;
    int lg = lane >> 4;

    if (tid < 32) {
        float s = 0.f;
#pragma unroll 1
        for (int i = 0; i < 19; ++i) s += bskv[i * 32 + tid];
        bsum[tid] = s;
    }

    int posGlob = posG + w * 16 + lr;

    f32x4 dsk0 = {0.f, 0.f, 0.f, 0.f};
    f32x4 dsk1 = {0.f, 0.f, 0.f, 0.f};

#pragma unroll
    for (int kt = 0; kt < 10; ++kt) {
        int i   = kt * 2 + (lg >> 1);
        int ic0 = (lg & 1) * 8;
        half8v bfr = {0, 0, 0, 0, 0, 0, 0, 0};
        half8v af0 = {0, 0, 0, 0, 0, 0, 0, 0};
        half8v af1 = {0, 0, 0, 0, 0, 0, 0, 0};
        if (i < 19) {
            bfr = *(const half8v*)(Hf + (size_t)i * HFE + (size_t)posGlob * 16 + ic0);

            const float4* wp0 = (const float4*)(Wsk + (size_t)i * 512 + (0 * 16 + lr) * 16 + ic0);
            const float4* wp1 = (const float4*)(Wsk + (size_t)i * 512 + (1 * 16 + lr) * 16 + ic0);
            float4 a0 = wp0[0], a1 = wp0[1];
            float4 c0v = wp1[0], c1v = wp1[1];
            af0[0] = (_Float16)a0.x; af0[1] = (_Float16)a0.y;
            af0[2] = (_Float16)a0.z; af0[3] = (_Float16)a0.w;
            af0[4] = (_Float16)a1.x; af0[5] = (_Float16)a1.y;
            af0[6] = (_Float16)a1.z; af0[7] = (_Float16)a1.w;
            af1[0] = (_Float16)c0v.x; af1[1] = (_Float16)c0v.y;
            af1[2] = (_Float16)c0v.z; af1[3] = (_Float16)c0v.w;
            af1[4] = (_Float16)c1v.x; af1[5] = (_Float16)c1v.y;
            af1[6] = (_Float16)c1v.z; af1[7] = (_Float16)c1v.w;
        }
        dsk0 = __builtin_amdgcn_mfma_f32_16x16x32_f16(af0, bfr, dsk0, 0, 0, 0);
        dsk1 = __builtin_amdgcn_mfma_f32_16x16x32_f16(af1, bfr, dsk1, 0, 0, 0);
    }

    __syncthreads();

    {
        int posL = w * 16 + lr;
#pragma unroll
        for (int r = 0; r < 4; ++r) {
            int sc0 = 0 * 16 + lg * 4 + r;
            int sc1 = 1 * 16 + lg * 4 + r;
            sv_lds[posL][sc0] = fmaxf(dsk0[r] + bsum[sc0], 0.f);
            sv_lds[posL][sc1] = fmaxf(dsk1[r] + bsum[sc1], 0.f);
        }
    }
    __syncthreads();

    {
        float sv[32];
#pragma unroll
        for (int sch = 0; sch < 32; ++sch) sv[sch] = sv_lds[lane][sch];

        float r16[16];
#pragma unroll
        for (int a = 0; a < 16; ++a) {
            int ac = w * 16 + a;
            float acc = bagg[ac];
#pragma unroll
            for (int sch = 0; sch < 32; ++sch)
                acc = fmaf(Wagg[ac * 32 + sch], sv[sch], acc);
            r16[a] = fmaxf(acc, 0.f);
        }
#pragma unroll
        for (int q = 0; q < 8; ++q) {
            unsigned pk = (unsigned)f16bits(r16[2 * q]) |
                          ((unsigned)f16bits(r16[2 * q + 1]) << 16);
            int icbyte = (w * 16 + 2 * q) * 2;
            int addr   = lane * 128 + (icbyte ^ ((lane & 7) << 4));
            *(unsigned*)(&agg_bu[addr >> 1]) = pk;
        }
    }
    __syncthreads();

    int c0 = w * 64;
    half8v afr[4][2];
#pragma unroll
    for (int ct = 0; ct < 4; ++ct) {
#pragma unroll
        for (int kf = 0; kf < 2; ++kf) {
            int cls = c0 + ct * 16 + lr;
            int k0  = kf * 32 + lg * 8;
            const float4* wp = (const float4*)(Wout + (size_t)cls * 64 + k0);
            float4 w0 = wp[0], w1 = wp[1];
            half8v af;
            af[0] = (_Float16)w0.x; af[1] = (_Float16)w0.y;
            af[2] = (_Float16)w0.z; af[3] = (_Float16)w0.w;
            af[4] = (_Float16)w1.x; af[5] = (_Float16)w1.y;
            af[6] = (_Float16)w1.z; af[7] = (_Float16)w1.w;
            afr[ct][kf] = af;
        }
    }

    f32x4 acc[4][4];
#pragma unroll
    for (int pt = 0; pt < 4; ++pt) {
        int pos = pt * 16 + lr;
        int sw  = (pos & 7) << 4;
        const half8v* bp0 = (const half8v*)(&agg_bu[(pos * 128 + ((0 * 64 + lg * 16) ^ sw)) >> 1]);
        const half8v* bp1 = (const half8v*)(&agg_bu[(pos * 128 + ((1 * 64 + lg * 16) ^ sw)) >> 1]);
        half8v bf0 = *bp0;
        half8v bf1 = *bp1;
#pragma unroll
        for (int ct = 0; ct < 4; ++ct) {
            f32x4 c;
#pragma unroll
            for (int r = 0; r < 4; ++r) c[r] = bout[c0 + ct * 16 + lg * 4 + r];
            c = __builtin_amdgcn_mfma_f32_16x16x32_f16(afr[ct][0], bf0, c, 0, 0, 0);
            c = __builtin_amdgcn_mfma_f32_16x16x32_f16(afr[ct][1], bf1, c, 0, 0, 0);
            acc[pt][ct] = c;
        }
    }

#pragma unroll
    for (int pt = 0; pt < 4; ++pt) {
        float m = -1e30f;
#pragma unroll
        for (int ct = 0; ct < 4; ++ct)
#pragma unroll
            for (int r = 0; r < 4; ++r) m = fmaxf(m, acc[pt][ct][r]);
        m = fmaxf(m, __shfl_xor(m, 16));
        m = fmaxf(m, __shfl_xor(m, 32));
        float s = 0.f;
#pragma unroll
        for (int ct = 0; ct < 4; ++ct)
#pragma unroll
            for (int r = 0; r < 4; ++r) s += __expf(acc[pt][ct][r] - m);
        s += __shfl_xor(s, 16);
        s += __shfl_xor(s, 32);
        int pos = pt * 16 + lr;
        red_m[pos][w] = m;
        red_s[pos][w] = s;
    }
    __syncthreads();

    // logZ per pt tile (position pt*16+lr)
    float logZv[4];
#pragma unroll
    for (int pt = 0; pt < 4; ++pt) {
        int pos = pt * 16 + lr;
        float M = fmaxf(fmaxf(red_m[pos][0], red_m[pos][1]),
                        fmaxf(red_m[pos][2], red_m[pos][3]));
        float S = 0.f;
#pragma unroll
        for (int k = 0; k < 4; ++k) S += red_s[pos][k] * __expf(red_m[pos][k] - M);
        logZv[pt] = M + __logf(S);
    }

    // transposed, fully-coalesced write: per ct-tile stage into per-wave LDS
    // ([16 cls][64 pos]) then store 256B-contiguous rows (wave-synchronous).
#pragma unroll
    for (int ct = 0; ct < 4; ++ct) {
#pragma unroll
        for (int pt = 0; pt < 4; ++pt)
#pragma unroll
            for (int r = 0; r < 4; ++r)
                tr_lds[w][lg * 4 + r][pt * 16 + lr] = acc[pt][ct][r] - logZv[pt];
        // same-wave LDS write->read: ordered by hardware (lgkmcnt), no barrier
#pragma unroll
        for (int j = 0; j < 16; ++j) {
            int cls = c0 + ct * 16 + j;
            out[((size_t)(b * 256 + cls)) * NPOS + nb + lane] = tr_lds[w][j][lane];
        }
    }
}

// ======================================================================
// R8 fallback path (ch-major, skip-RMW, bf16 final) — safety net only
// ======================================================================
__global__ __launch_bounds__(256) void init_kernel2(
    const int* __restrict__ x_int, const float* __restrict__ W0,
    const float* __restrict__ b0, float* __restrict__ h)
{
    int t0 = (blockIdx.x * 256 + threadIdx.x) * 2;
    int n0 = t0 & (NPOS - 1);
    const float sc = 1.f / 32768.f;
    float xs0  = (n0 >= 1) ? (float)x_int[t0 - 1] * sc : 0.f;
    float xs1  = (float)x_int[t0] * sc;
    float xsp0 = (n0 >= 2) ? (float)x_int[t0 - 2] * sc : 0.f;
    float xsp1 = xs0;
#pragma unroll
    for (int c = 0; c < 16; ++c) {
        float2 o;
        o.x = xs0 + W0[c * 2 + 0] * xsp0 + W0[c * 2 + 1] * xs0 + b0[c];
        o.y = xs1 + W0[c * 2 + 0] * xsp1 + W0[c * 2 + 1] * xs1 + b0[c];
        *(float2*)(h + (size_t)c * TOTAL + t0) = o;
    }
}

__global__ __launch_bounds__(256, 2) void layer_kernel2(
    const float* __restrict__ hIn, float* __restrict__ hOut,
    float* __restrict__ skip,
    const float* __restrict__ wf, const float* __restrict__ bfv,
    const float* __restrict__ wg, const float* __restrict__ bgv,
    const float* __restrict__ wsk, const float* __restrict__ bskv,
    int d, int firstLayer)
{
    int t0 = (blockIdx.x * 256 + threadIdx.x) * 2;
    int n0 = t0 & (NPOS - 1);

    float2 hc[16], hp[16];
#pragma unroll
    for (int ic = 0; ic < 16; ++ic)
        hc[ic] = *(const float2*)(hIn + (size_t)ic * TOTAL + t0);

    if (d == 1) {
        bool v = (n0 >= 1);
        int tm = v ? (t0 - 1) : t0;
#pragma unroll
        for (int ic = 0; ic < 16; ++ic) {
            float x = hIn[(size_t)ic * TOTAL + tm];
            hp[ic].x = v ? x : 0.f;
            hp[ic].y = hc[ic].x;
        }
    } else {
        bool v = (n0 >= d);
        int tm = v ? (t0 - d) : t0;
#pragma unroll
        for (int ic = 0; ic < 16; ++ic) {
            float2 x = *(const float2*)(hIn + (size_t)ic * TOTAL + tm);
            hp[ic].x = v ? x.x : 0.f;
            hp[ic].y = v ? x.y : 0.f;
        }
    }

    float2 fa[16], ga[16];
#pragma unroll
    for (int c = 0; c < 16; ++c) {
        fa[c].x = fa[c].y = bfv[c];
        ga[c].x = ga[c].y = bgv[c];
    }
#pragma unroll
    for (int c = 0; c < 16; ++c) {
#pragma unroll
        for (int ic = 0; ic < 16; ++ic) {
            float wf0 = wf[(c * 16 + ic) * 2 + 0];
            float wf1 = wf[(c * 16 + ic) * 2 + 1];
            float wg0 = wg[(c * 16 + ic) * 2 + 0];
            float wg1 = wg[(c * 16 + ic) * 2 + 1];
            fa[c].x = fmaf(wf0, hp[ic].x, fa[c].x);
            fa[c].x = fmaf(wf1, hc[ic].x, fa[c].x);
            fa[c].y = fmaf(wf0, hp[ic].y, fa[c].y);
            fa[c].y = fmaf(wf1, hc[ic].y, fa[c].y);
            ga[c].x = fmaf(wg0, hp[ic].x, ga[c].x);
            ga[c].x = fmaf(wg1, hc[ic].x, ga[c].x);
            ga[c].y = fmaf(wg0, hp[ic].y, ga[c].y);
            ga[c].y = fmaf(wg1, hc[ic].y, ga[c].y);
        }
    }

#pragma unroll
    for (int c = 0; c < 16; ++c) {
        float2 o;
        o.x = fmaf(fast_tanh(fa[c].x), fast_sigmoid(ga[c].x), hc[c].x);
        o.y = fmaf(fast_tanh(fa[c].y), fast_sigmoid(ga[c].y), hc[c].y);
        *(float2*)(hOut + (size_t)c * TOTAL + t0) = o;
    }

#pragma unroll
    for (int sch = 0; sch < 32; ++sch) {
        float2 acc;
        acc.x = acc.y = bskv[sch];
#pragma unroll
        for (int ic = 0; ic < 16; ++ic) {
            float wv = wsk[sch * 16 + ic];
            acc.x = fmaf(wv, hc[ic].x, acc.x);
            acc.y = fmaf(wv, hc[ic].y, acc.y);
        }
        float* sp = skip + (size_t)sch * TOTAL + t0;
        if (firstLayer) {
            *(float2*)sp = acc;
        } else {
            float2 old = *(const float2*)sp;
            acc.x += old.x; acc.y += old.y;
            *(float2*)sp = acc;
        }
    }
}

__global__ __launch_bounds__(256, 2) void final_kernel(
    const float* __restrict__ skip,
    const float* __restrict__ Wagg, const float* __restrict__ bagg,
    const float* __restrict__ Wout, const float* __restrict__ bout,
    float* __restrict__ out)
{
    __shared__ unsigned short agg_bu[64 * 64];
    __shared__ float red_m[64][5];
    __shared__ float red_s[64][5];

    int tid  = threadIdx.x;
    int lane = tid & 63;
    int w    = tid >> 6;
    int posG = blockIdx.x * 64;
    int b    = posG >> LOG2N;
    int nb   = posG & (NPOS - 1);

    {
        int pos = posG + lane;
        float sv[32];
#pragma unroll
        for (int sch = 0; sch < 32; ++sch)
            sv[sch] = fmaxf(skip[(size_t)sch * TOTAL + pos], 0.f);

        float r16[16];
#pragma unroll
        for (int a = 0; a < 16; ++a) {
            int ac = w * 16 + a;
            float acc = bagg[ac];
#pragma unroll
            for (int sch = 0; sch < 32; ++sch)
                acc = fmaf(Wagg[ac * 32 + sch], sv[sch], acc);
            r16[a] = fmaxf(acc, 0.f);
        }
#pragma unroll
        for (int q = 0; q < 8; ++q) {
            unsigned pk = (unsigned)bf16rne(r16[2 * q]) |
                          ((unsigned)bf16rne(r16[2 * q + 1]) << 16);
            int icbyte = (w * 16 + 2 * q) * 2;
            int addr   = lane * 128 + (icbyte ^ ((lane & 7) << 4));
            *(unsigned*)(&agg_bu[addr >> 1]) = pk;
        }
    }
    __syncthreads();

    int lr = lane & 15;
    int lg = lane >> 4;
    int c0 = w * 64;
    short8v afr[4][2];
#pragma unroll
    for (int ct = 0; ct < 4; ++ct) {
#pragma unroll
        for (int kf = 0; kf < 2; ++kf) {
            int cls = c0 + ct * 16 + lr;
            int k0  = kf * 32 + lg * 8;
            const float4* wp = (const float4*)(Wout + (size_t)cls * 64 + k0);
            float4 w0 = wp[0], w1 = wp[1];
            short8v af;
            af[0] = (short)bf16rne(w0.x); af[1] = (short)bf16rne(w0.y);
            af[2] = (short)bf16rne(w0.z); af[3] = (short)bf16rne(w0.w);
            af[4] = (short)bf16rne(w1.x); af[5] = (short)bf16rne(w1.y);
            af[6] = (short)bf16rne(w1.z); af[7] = (short)bf16rne(w1.w);
            afr[ct][kf] = af;
        }
    }

    f32x4 acc[4][4];
#pragma unroll
    for (int pt = 0; pt < 4; ++pt) {
        int pos = pt * 16 + lr;
        int sw  = (pos & 7) << 4;
        const short8v* bp0 = (const short8v*)(&agg_bu[(pos * 128 + ((0 * 64 + lg * 16) ^ sw)) >> 1]);
        const short8v* bp1 = (const short8v*)(&agg_bu[(pos * 128 + ((1 * 64 + lg * 16) ^ sw)) >> 1]);
        short8v bf0 = *bp0;
        short8v bf1 = *bp1;
#pragma unroll
        for (int ct = 0; ct < 4; ++ct) {
            f32x4 c;
#pragma unroll
            for (int r = 0; r < 4; ++r) c[r] = bout[c0 + ct * 16 + lg * 4 + r];
            c = __builtin_amdgcn_mfma_f32_16x16x32_bf16(afr[ct][0], bf0, c, 0, 0, 0);
            c = __builtin_amdgcn_mfma_f32_16x16x32_bf16(afr[ct][1], bf1, c, 0, 0, 0);
            acc[pt][ct] = c;
        }
    }

#pragma unroll
    for (int pt = 0; pt < 4; ++pt) {
        float m = -1e30f;
#pragma unroll
        for (int ct = 0; ct < 4; ++ct)
#pragma unroll
            for (int r = 0; r < 4; ++r) m = fmaxf(m, acc[pt][ct][r]);
        m = fmaxf(m, __shfl_xor(m, 16));
        m = fmaxf(m, __shfl_xor(m, 32));
        float s = 0.f;
#pragma unroll
        for (int ct = 0; ct < 4; ++ct)
#pragma unroll
            for (int r = 0; r < 4; ++r) s += __expf(acc[pt][ct][r] - m);
        s += __shfl_xor(s, 16);
        s += __shfl_xor(s, 32);
        int pos = pt * 16 + lr;
        red_m[pos][w] = m;
        red_s[pos][w] = s;
    }
    __syncthreads();

#pragma unroll
    for (int pt = 0; pt < 4; ++pt) {
        int pos = pt * 16 + lr;
        float M = fmaxf(fmaxf(red_m[pos][0], red_m[pos][1]),
                        fmaxf(red_m[pos][2], red_m[pos][3]));
        float S = 0.f;
#pragma unroll
        for (int k = 0; k < 4; ++k) S += red_s[pos][k] * __expf(red_m[pos][k] - M);
        float logZ = M + __logf(S);

        int n = nb + pos;
#pragma unroll
        for (int ct = 0; ct < 4; ++ct) {
#pragma unroll
            for (int r = 0; r < 4; ++r) {
                int cls = c0 + ct * 16 + lg * 4 + r;
                out[((size_t)(b * 256 + cls)) * NPOS + n] = acc[pt][ct][r] - logZ;
            }
        }
    }
}

extern "C" void kernel_launch(void* const* d_in, const int* in_sizes, int n_in,
                              void* d_out, int out_size, void* d_ws, size_t ws_size,
                              hipStream_t stream)
{
    const int*   x_int = (const int*)  d_in[0];
    const float* W0    = (const float*)d_in[1];
    const float* b0    = (const float*)d_in[2];
    const float* Wf    = (const float*)d_in[3];
    const float* bfv   = (const float*)d_in[4];
    const float* Wg    = (const float*)d_in[5];
    const float* bgv   = (const float*)d_in[6];
    const float* Wsk   = (const float*)d_in[7];
    const float* bskv  = (const float*)d_in[8];
    const float* Wagg  = (const float*)d_in[9];
    const float* bagg  = (const float*)d_in[10];
    const float* Wout  = (const float*)d_in[11];
    const float* bout  = (const float*)d_in[12];
    float* out = (float*)d_out;

    const size_t needF16 = 19 * HFE * sizeof(_Float16);   // 152 MiB
    const int grid2 = TOTAL / (256 * 2);                  // 512 blocks

    if (ws_size >= needF16) {
        // ---------- fp16-ladder with fused MFMA layer pairs ----------
        _Float16* Hf = (_Float16*)d_ws;    // H_i at Hf + i*HFE

        init_f16<<<grid2, 256, 0, stream>>>(x_int, W0, b0, Hf);
        for (int p = 0; p < 9; ++p) {
            int iA = 2 * p, iB = 2 * p + 1;
            int dA = 1 << ((iA + 1) % 10);
            int dB = 1 << ((iB + 1) % 10);
            int haloR = (dB + 15) & ~15;
            pair_mfma<<<TOTAL / 256, 256, 0, stream>>>(
                Hf + (size_t)iA * HFE,
                Hf + (size_t)(iA + 1) * HFE, Hf + (size_t)(iB + 1) * HFE,
                Wf + (size_t)iA * 512, bfv + (size_t)iA * 16,
                Wg + (size_t)iA * 512, bgv + (size_t)iA * 16,
                Wf + (size_t)iB * 512, bfv + (size_t)iB * 16,
                Wg + (size_t)iB * 512, bgv + (size_t)iB * 16,
                dA, dB, haloR);
        }
        final_f16<<<TOTAL / 64, 256, 0, stream>>>(
            Hf, Wsk, bskv, Wagg, bagg, Wout, bout, out);
    } else {
        // ---------- R8 fallback (ch-major, skip-RMW) ----------
        const size_t skE = (size_t)32 * TOTAL;
        float* skipb = (float*)d_ws;
        float *hA, *hB;
        if (ws_size >= (skE + 2 * HE) * sizeof(float)) {
            hA = skipb + skE;
            hB = hA + HE;
        } else {
            hA = out + ((size_t)out_size - 2 * HE);
            hB = hA + HE;
        }

        init_kernel2<<<grid2, 256, 0, stream>>>(x_int, W0, b0, hA);
        float* hin = hA;
        float* hout = hB;
        for (int i = 0; i < 19; ++i) {
            int d = 1 << ((i + 1) % 10);
            layer_kernel2<<<grid2, 256, 0, stream>>>(
                hin, hout, skipb,
                Wf + (size_t)i * 512, bfv + (size_t)i * 16,
                Wg + (size_t)i * 512, bgv + (size_t)i * 16,
                Wsk + (size_t)i * 512, bskv + (size_t)i * 32,
                d, (i == 0) ? 1 : 0);
            float* tmp = hin; hin = hout; hout = tmp;
        }
        final_kernel<<<TOTAL / 64, 256, 0, stream>>>(
            skipb, Wagg, bagg, Wout, bout, out);
    }
}